// Round 12
// baseline (1428.724 us; speedup 1.0000x reference)
//
#include <hip/hip_runtime.h>
#include <math.h>

// R11: all-register transformer via operand-role algebra (16x16x16 MFMA):
//   C-frag(X) == B-operand X ; C-frag(X) as A-operand == X^T.
// Residual stream kept TRANSPOSED (v = h^T, 4 C-frag tiles: rows d, cols tok).
//   Qt = Wq*h^T (A=pack,B=v) ; Kt likewise ; V = h*Wv^T (A=v,B=pack)
//   S^T = mfma(A=Kt, B=Qt) ; softmax in-lane (unchanged) ; O^T = mfma(A=V, B=aP)
//   v += ow*O^T ; F^T = W1*h'^T (+ReLU) ; v += W2*F^T   -- ZERO LDS round trips,
// zero barriers in the seq loop. LDS = 12KB (conv staging ∪ g) -> 1024 blocks
// x 256 thr = 4 blocks/CU = 16 waves/CU (2x occupancy). Weights/bias/LN/pe
// pre-packed into d_ws as per-lane fragments by wpack.

typedef __attribute__((ext_vector_type(4))) short s4v;
typedef __attribute__((ext_vector_type(4))) float f4v;

#define MFMA16(A, B, C) __builtin_amdgcn_mfma_f32_16x16x16bf16_1k((A), (B), (C), 0, 0, 0)

static __device__ __forceinline__ unsigned short f2b(float f) {
  return __builtin_bit_cast(unsigned short, (__bf16)f);
}
static __device__ __forceinline__ s4v c4(f4v v) {
  s4v r;
  r[0] = (short)f2b(v[0]); r[1] = (short)f2b(v[1]);
  r[2] = (short)f2b(v[2]); r[3] = (short)f2b(v[3]);
  return r;
}

// ---------------- ws layout ----------------
// W tiles: T = 0..387, 512B each: lane l holds s4v = W[jo*16+(l&15)][c*16+(l>>4)*4+e]
//   0..95   qkv: T = l*48 + mat*16 + jo*4 + c   (mat 0=Q,1=K,2=V)
//   96..127 ow : T = 96 + l*16 + jo*4 + c
//   128..131 win: T = 128 + jo                  (IN=4, zeros beyond)
//   132..259 ff1: T = 132 + l*64 + fo*4 + c
//   260..387 ff2: T = 260 + l*64 + jo*16 + c    (IN=256)
// F frags: F = 0..103, 1024B each: lane l holds float4 (index i -> row (l>>4)*4+i)
//   0..3 pe(jo) | 4..7 wout(jo) | 8..39 LN: 8+l*16+a*4+jo (a:ln1g,ln1b,ln2g,ln2b)
//   40..47 Qbias | 48..55 Kbias | 56..63 ob | 64..95 ff1b(l,fo) | 96..103 ff2b
#define WBYTES (388 * 512)

__global__ __launch_bounds__(256) void wpack(
    const float* __restrict__ qkv_w, const float* __restrict__ ow_,
    const float* __restrict__ ff1_w, const float* __restrict__ ff2_w,
    const float* __restrict__ w_in,  const float* __restrict__ qkv_b,
    const float* __restrict__ ob_,   const float* __restrict__ ln1_g,
    const float* __restrict__ ln1_b, const float* __restrict__ ff1_b,
    const float* __restrict__ ff2_b, const float* __restrict__ ln2_g,
    const float* __restrict__ ln2_b, const float* __restrict__ w_out,
    char* __restrict__ ws)
{
  int gid = blockIdx.x * 256 + threadIdx.x;
  int lane = gid & 63, idx = gid >> 6;
  int ln = lane & 15, grp = lane >> 4;
  if (idx < 388) {
    const float* src; int IN = 64, row, colbase;
    if (idx < 96) {
      int l = idx / 48, r = idx % 48, mat = r / 16, q = r % 16, jo = q / 4, c = q % 4;
      src = qkv_w + l * 12288 + mat * 4096; row = jo * 16 + ln; colbase = c * 16 + grp * 4;
    } else if (idx < 128) {
      int t = idx - 96, l = t / 16, q = t % 16, jo = q / 4, c = q % 4;
      src = ow_ + l * 4096; row = jo * 16 + ln; colbase = c * 16 + grp * 4;
    } else if (idx < 132) {
      int jo = idx - 128; src = w_in; IN = 4; row = jo * 16 + ln; colbase = grp * 4;
    } else if (idx < 260) {
      int t = idx - 132, l = t / 64, q = t % 64, fo = q / 4, c = q % 4;
      src = ff1_w + l * 16384; row = fo * 16 + ln; colbase = c * 16 + grp * 4;
    } else {
      int t = idx - 260, l = t / 64, q = t % 64, jo = q / 16, c = q % 16;
      src = ff2_w + l * 16384; IN = 256; row = jo * 16 + ln; colbase = c * 16 + grp * 4;
    }
    unsigned short h[4];
#pragma unroll
    for (int e = 0; e < 4; ++e) {
      int ci = colbase + e;
      h[e] = (ci < IN) ? f2b(src[row * IN + ci]) : (unsigned short)0;
    }
    unsigned lo = (unsigned)h[0] | ((unsigned)h[1] << 16);
    unsigned hi = (unsigned)h[2] | ((unsigned)h[3] << 16);
    *(uint2*)(ws + idx * 512 + lane * 8) = make_uint2(lo, hi);
  } else if (idx < 388 + 104) {
    int F = idx - 388, i0 = grp * 4;
    float val[4];
    if (F < 4) {
      int jo = F;
#pragma unroll
      for (int i = 0; i < 4; ++i) {
        int d = jo * 16 + i0 + i;
        float freq = expf(-(float)(d & ~1) * (9.210340371976184f / 64.f));
        float a = (float)ln * freq;
        val[i] = (ln < 12) ? ((d & 1) ? cosf(a) : sinf(a)) : 0.f;
      }
    } else if (F < 8) {
      int jo = F - 4;
      for (int i = 0; i < 4; ++i) val[i] = w_out[jo * 16 + i0 + i];
    } else if (F < 40) {
      int t = F - 8, l = t / 16, a = (t % 16) / 4, jo = t % 4;
      const float* p = (a == 0 ? ln1_g : a == 1 ? ln1_b : a == 2 ? ln2_g : ln2_b) + l * 64;
      for (int i = 0; i < 4; ++i) val[i] = p[jo * 16 + i0 + i];
    } else if (F < 48) {
      int t = F - 40, l = t / 4, jo = t % 4;
      for (int i = 0; i < 4; ++i) val[i] = qkv_b[l * 192 + jo * 16 + i0 + i];
    } else if (F < 56) {
      int t = F - 48, l = t / 4, jo = t % 4;
      for (int i = 0; i < 4; ++i) val[i] = qkv_b[l * 192 + 64 + jo * 16 + i0 + i];
    } else if (F < 64) {
      int t = F - 56, l = t / 4, jo = t % 4;
      for (int i = 0; i < 4; ++i) val[i] = ob_[l * 64 + jo * 16 + i0 + i];
    } else if (F < 96) {
      int t = F - 64, l = t / 16, fo = t % 16;
      for (int i = 0; i < 4; ++i) val[i] = ff1_b[l * 256 + fo * 16 + i0 + i];
    } else {
      int t = F - 96, l = t / 4, jo = t % 4;
      for (int i = 0; i < 4; ++i) val[i] = ff2_b[l * 64 + jo * 16 + i0 + i];
    }
    *(float4*)(ws + WBYTES + F * 1024 + lane * 16) = make_float4(val[0], val[1], val[2], val[3]);
  }
}

// transposed-stream LayerNorm: stats per token (=lane column ln), d spread over
// (jo tiles x grp x i). 2 shfls per stat.
static __device__ __forceinline__ void lnorm_t(f4v v[4], s4v vb[4],
                                               const char* wsF, int gbase, int bbase, int lane) {
  float s = 0.f;
#pragma unroll
  for (int jo = 0; jo < 4; ++jo)
#pragma unroll
    for (int i = 0; i < 4; ++i) s += v[jo][i];
  s += __shfl_xor(s, 16); s += __shfl_xor(s, 32);
  float mean = s * (1.f / 64.f);
  float q = 0.f;
#pragma unroll
  for (int jo = 0; jo < 4; ++jo)
#pragma unroll
    for (int i = 0; i < 4; ++i) { float d = v[jo][i] - mean; q = fmaf(d, d, q); }
  q += __shfl_xor(q, 16); q += __shfl_xor(q, 32);
  float rs = rsqrtf(q * (1.f / 64.f) + 1e-5f);
#pragma unroll
  for (int jo = 0; jo < 4; ++jo) {
    f4v g = *(const f4v*)(wsF + (gbase + jo) * 1024 + lane * 16);
    f4v b = *(const f4v*)(wsF + (bbase + jo) * 1024 + lane * 16);
#pragma unroll
    for (int i = 0; i < 4; ++i) v[jo][i] = fmaf((v[jo][i] - mean) * rs, g[i], b[i]);
    vb[jo] = c4(v[jo]);
  }
}

__global__ __launch_bounds__(256) void prithvi_fused(
    const float* __restrict__ x,     const float* __restrict__ conv_w,
    const float* __restrict__ bn_g,  const float* __restrict__ bn_b,
    const float* __restrict__ bn_m,  const float* __restrict__ bn_v,
    const float* __restrict__ qkv_b, const float* __restrict__ b_out,
    const char* __restrict__ ws,     float* __restrict__ out)
{
  __shared__ __align__(16) float sbuf[3072];   // 12KB staging; g2 (6KB) aliases after conv
  unsigned short* g2 = (unsigned short*)sbuf;

  const int blk = blockIdx.x, sp = blk >> 2, qq = blk & 3;
  const int tid = threadIdx.x, lane = tid & 63, wave = tid >> 6;

  // ---- conv: 1 output channel/thread (this quarter's 256 channels), x staged in 4 passes ----
  {
    float acc[12];
#pragma unroll
    for (int t = 0; t < 12; ++t) acc[t] = 0.f;
    const int c = tid >> 6, jj = tid & 63;
    const int oc = c * 256 + qq * 64 + jj;
    const float* wrow = conv_w + (size_t)oc * 1024;
#pragma unroll 1
    for (int p = 0; p < 4; ++p) {
      for (int ch2 = tid; ch2 < 3072; ch2 += 256) {
        int e = ch2 / 12, t = ch2 - 12 * e;
        sbuf[t * 256 + e] = x[(size_t)((p * 256 + e) * 12 + t) * 256 + sp];
      }
      __syncthreads();
      for (int eb = 0; eb < 256; eb += 4) {
        float4 w4 = *(const float4*)(wrow + p * 256 + eb);
#pragma unroll
        for (int t = 0; t < 12; ++t) {
          float4 xv = *(const float4*)&sbuf[t * 256 + eb];
          acc[t] = fmaf(xv.x, w4.x, acc[t]);
          acc[t] = fmaf(xv.y, w4.y, acc[t]);
          acc[t] = fmaf(xv.z, w4.z, acc[t]);
          acc[t] = fmaf(xv.w, w4.w, acc[t]);
        }
      }
      __syncthreads();
    }
    // BN + exact GELU -> g2[s_local=jj][t][c]  (aliases sbuf; staging reads done)
    float sc = bn_g[oc] * rsqrtf(bn_v[oc] + 1e-5f);
    float sh = fmaf(-bn_m[oc], sc, bn_b[oc]);
#pragma unroll
    for (int t = 0; t < 12; ++t) {
      float z = fmaf(acc[t], sc, sh);
      g2[jj * 48 + t * 4 + c] = f2b(0.5f * z * (1.f + erff(z * 0.70710678118654752f)));
    }
  }
  __syncthreads();   // g2 read-only from here; NO barriers below

  // ---- phase 3: all-register transformer, 16 seqs per wave ----
  const int ln = lane & 15, grp = lane >> 4;
  const char* wsF = ws + WBYTES;
#define WT(T) __builtin_bit_cast(s4v, *(const uint2*)(ws + (T) * 512 + lane * 8))
#define FR(F) (*(const f4v*)(wsF + (F) * 1024 + lane * 16))
  const int lnc = (ln < 12) ? ln : 11;
  const float bo0 = b_out[0];
  const f4v z4 = {0.f, 0.f, 0.f, 0.f};

#pragma unroll 1
  for (int itr = 0; itr < 16; ++itr) {
    const int sl = wave * 16 + itr;   // 0..63
    const int s = qq * 64 + sl;       // 0..255
    // h0^T = win * g^T + pe^T : A=win-pack (zeros for k>=4), B = per-token g quad
    s4v gb = __builtin_bit_cast(s4v, *(const uint2*)(g2 + sl * 48 + lnc * 4));
    f4v v[4]; s4v vb[4];
#pragma unroll
    for (int jo = 0; jo < 4; ++jo) {
      v[jo] = MFMA16(WT(128 + jo), gb, FR(jo));
      vb[jo] = c4(v[jo]);
    }

#pragma unroll 1
    for (int l = 0; l < 2; ++l) {
      // ---- QKV: Qt,Kt = W*h^T (transposed); V = h*Wv^T (normal) ----
      s4v Qt[4], Kt[4], Vf[4];
#pragma unroll
      for (int jo = 0; jo < 4; ++jo) {
        f4v qc = FR(40 + l * 4 + jo);
        f4v kc = FR(48 + l * 4 + jo);
        float bb = qkv_b[l * 192 + 128 + jo * 16 + ln];
        f4v vc = {bb, bb, bb, bb};
#pragma unroll
        for (int c = 0; c < 4; ++c) {
          qc = MFMA16(WT(l * 48 + jo * 4 + c), vb[c], qc);
          kc = MFMA16(WT(l * 48 + 16 + jo * 4 + c), vb[c], kc);
          vc = MFMA16(vb[c], WT(l * 48 + 32 + jo * 4 + c), vc);
        }
        Qt[jo] = c4(qc); Kt[jo] = c4(kc); Vf[jo] = c4(vc);
      }
      // ---- attention: S^T = mfma(A=Kt, B=Qt); softmax; O^T = mfma(A=V, B=aP) ----
      s4v Otb[4];
#pragma unroll
      for (int hh = 0; hh < 4; ++hh) {
        f4v sc = MFMA16(Kt[hh], Qt[hh], z4);   // lane: S^T[k=grp*4+i][q=ln]
        float e0, e1, e2, e3;
        if (grp == 3) { e0 = e1 = e2 = e3 = 0.f; }
        else {
          e0 = __expf(sc[0] * 0.25f); e1 = __expf(sc[1] * 0.25f);
          e2 = __expf(sc[2] * 0.25f); e3 = __expf(sc[3] * 0.25f);
        }
        float sm = (e0 + e1) + (e2 + e3);
        sm += __shfl_xor(sm, 16);
        sm += __shfl_xor(sm, 32);
        float inv = 1.f / sm;
        s4v aP;
        aP[0] = (short)f2b(e0 * inv); aP[1] = (short)f2b(e1 * inv);
        aP[2] = (short)f2b(e2 * inv); aP[3] = (short)f2b(e3 * inv);
        Otb[hh] = c4(MFMA16(Vf[hh], aP, z4));  // O^T head hh (rows dv, cols q)
      }
      // ---- O-proj (transposed) + bias + residual: v += ow * O^T ----
#pragma unroll
      for (int jo = 0; jo < 4; ++jo) {
        f4v cc = v[jo] + FR(56 + l * 4 + jo);
#pragma unroll
        for (int c = 0; c < 4; ++c)
          cc = MFMA16(WT(96 + l * 16 + jo * 4 + c), Otb[c], cc);
        v[jo] = cc;
      }
      // ---- LN1 ----
      lnorm_t(v, vb, wsF, 8 + l * 16, 12 + l * 16, lane);
      // ---- FF: F^T = relu(W1*h^T + b1); v += W2*F^T + b2 (streamed fo-chunks) ----
      f4v a2[4];
#pragma unroll
      for (int jo = 0; jo < 4; ++jo) a2[jo] = v[jo] + FR(96 + l * 4 + jo);
#pragma unroll 1
      for (int c = 0; c < 16; ++c) {
        f4v fc = FR(64 + l * 16 + c);
#pragma unroll
        for (int cc = 0; cc < 4; ++cc)
          fc = MFMA16(WT(132 + l * 64 + c * 4 + cc), vb[cc], fc);
#pragma unroll
        for (int i = 0; i < 4; ++i) fc[i] = fmaxf(fc[i], 0.f);
        s4v ftb = c4(fc);
#pragma unroll
        for (int jo = 0; jo < 4; ++jo)
          a2[jo] = MFMA16(WT(260 + l * 64 + jo * 16 + c), ftb, a2[jo]);
      }
#pragma unroll
      for (int jo = 0; jo < 4; ++jo) v[jo] = a2[jo];
      // ---- LN2 ----
      lnorm_t(v, vb, wsF, 16 + l * 16, 20 + l * 16, lane);
    } // layer

    // ---- head: logit = mean_t(h) . w_out + b; h^T cols=tok ----
    {
      float p = 0.f;
#pragma unroll
      for (int jo = 0; jo < 4; ++jo) {
        f4v wo = FR(4 + jo);
#pragma unroll
        for (int i = 0; i < 4; ++i) p = fmaf(v[jo][i], wo[i], p);
      }
      p += __shfl_xor(p, 16);
      p += __shfl_xor(p, 32);        // now per-token full d-sum
      if (ln >= 12) p = 0.f;         // mask pad tokens
      p += __shfl_xor(p, 1);
      p += __shfl_xor(p, 2);
      p += __shfl_xor(p, 4);
      p += __shfl_xor(p, 8);         // sum over tokens
      if (lane == 0) {
        float logit = p * (1.f / 12.f) + bo0;
        int hf = ((sp >> 4) << 4) | (s >> 4);
        int wf = ((sp & 15) << 4) | (s & 15);
        out[hf * 256 + wf] = 1.f / (1.f + expf(-logit));
      }
    }
  } // seq loop
#undef WT
#undef FR
}

extern "C" void kernel_launch(void* const* d_in, const int* in_sizes, int n_in,
                              void* d_out, int out_size, void* d_ws, size_t ws_size,
                              hipStream_t stream) {
  (void)in_sizes; (void)n_in; (void)out_size; (void)ws_size;
  char* ws = (char*)d_ws;
  wpack<<<123, 256, 0, stream>>>(
      (const float*)d_in[7],  (const float*)d_in[9],  (const float*)d_in[13],
      (const float*)d_in[15], (const float*)d_in[6],  (const float*)d_in[8],
      (const float*)d_in[10], (const float*)d_in[11], (const float*)d_in[12],
      (const float*)d_in[14], (const float*)d_in[16], (const float*)d_in[17],
      (const float*)d_in[18], (const float*)d_in[19], ws);
  prithvi_fused<<<1024, 256, 0, stream>>>(
      (const float*)d_in[0], (const float*)d_in[1], (const float*)d_in[2],
      (const float*)d_in[3], (const float*)d_in[4], (const float*)d_in[5],
      (const float*)d_in[8], (const float*)d_in[20], ws,
      (float*)d_out);
}

// Round 13
// 1328.031 us; speedup vs baseline: 1.0758x; 1.0758x over previous
//
#include <hip/hip_runtime.h>
#include <math.h>

// R12 = R9 structure (best, 846us) + LDS squeeze for occupancy:
//  - 2 LDS buffers per seq (A,B; 4864B) instead of 3 (7296B):
//    h-frags reg-loaded before K overwrites A; O overwrites dead Q tiles in B;
//    FF runs as 4 chunks of 64 ff-dims (2176B) through B.
//  - 256-thr blocks (4 waves), quarter-cell (64 seqs), grid 1024.
//    Block LDS = 6KB g + 4x9728 = 44KB -> 3 blocks/CU = 12 waves/CU (was 8).
//  All math identical to R9 (MFMA32 bulk, S^T attention, 2-seq interleave).

typedef __attribute__((ext_vector_type(8))) short s8v;
typedef __attribute__((ext_vector_type(4))) short s4v;
typedef __attribute__((ext_vector_type(4))) float f4v;
typedef __attribute__((ext_vector_type(4))) unsigned int u4v;

#define MFMA32(A, B, C) __builtin_amdgcn_mfma_f32_16x16x32_bf16((A), (B), (C), 0, 0, 0)
#define MFMA16(A, B, C) __builtin_amdgcn_mfma_f32_16x16x16bf16_1k((A), (B), (C), 0, 0, 0)

static __device__ __forceinline__ unsigned short f2b(float f) {
  return __builtin_bit_cast(unsigned short, (__bf16)f);
}
static __device__ __forceinline__ float b2f(unsigned short h) {
  return __builtin_bit_cast(float, ((unsigned)h) << 16);
}

// ---- prologue: pack weights into MFMA B-fragment order (bf16) ----
// tile t: lane l holds B[k = kk*32 + (l>>4)*8 + e][n = j*16 + (l&15)], e=0..7
// bases: qkv l*24 + kk*12 + j | ow 48 + l*8 + kk*4 + j
//        ff1 64 + l*32 + kk*16 + j | ff2 128 + l*32 + kkg*4 + j
__global__ __launch_bounds__(256) void wpack(
    const float* __restrict__ qkv_w, const float* __restrict__ ow,
    const float* __restrict__ ff1_w, const float* __restrict__ ff2_w,
    unsigned int* __restrict__ ws) {
  int gid = blockIdx.x * 256 + threadIdx.x;   // 0..12287
  int tIdx = gid >> 6, lane = gid & 63;
  int ln = lane & 15, grp = lane >> 4;
  const float* src;
  if (tIdx < 48) {
    int l = tIdx / 24, r = tIdx % 24, kk = r / 12, j = r % 12;
    src = qkv_w + l * 12288 + (j * 16 + ln) * 64 + kk * 32 + grp * 8;
  } else if (tIdx < 64) {
    int u = tIdx - 48, l = u / 8, r = u % 8, kk = r / 4, j = r % 4;
    src = ow + l * 4096 + (j * 16 + ln) * 64 + kk * 32 + grp * 8;
  } else if (tIdx < 128) {
    int u = tIdx - 64, l = u / 32, r = u % 32, kk = r / 16, j = r % 16;
    src = ff1_w + l * 16384 + (j * 16 + ln) * 64 + kk * 32 + grp * 8;
  } else {
    int u = tIdx - 128, l = u / 32, r = u % 32, kk = r / 4, j = r % 4;
    src = ff2_w + l * 16384 + (j * 16 + ln) * 256 + kk * 32 + grp * 8;
  }
  unsigned p[4];
#pragma unroll
  for (int e = 0; e < 4; ++e)
    p[e] = (unsigned)f2b(src[2 * e]) | ((unsigned)f2b(src[2 * e + 1]) << 16);
  u4v val = {p[0], p[1], p[2], p[3]};
  *(u4v*)(ws + (size_t)gid * 4) = val;
}

__global__ __launch_bounds__(256) void prithvi_fused(
    const float* __restrict__ x,     const float* __restrict__ conv_w,
    const float* __restrict__ bn_g,  const float* __restrict__ bn_b,
    const float* __restrict__ bn_m,  const float* __restrict__ bn_v,
    const float* __restrict__ w_in,  const float* __restrict__ qkv_b,
    const float* __restrict__ ob,    const float* __restrict__ ln1_g,
    const float* __restrict__ ln1_b, const float* __restrict__ ff1_b,
    const float* __restrict__ ff2_b, const float* __restrict__ ln2_g,
    const float* __restrict__ ln2_b, const float* __restrict__ w_out,
    const float* __restrict__ b_out, const float* __restrict__ ws,
    float* __restrict__ out)
{
  // 6144B g2 + 38912B transformer region (conv staging 12288B aliases it)
  __shared__ __align__(16) char smem[45056];
  unsigned short* g2 = (unsigned short*)smem;          // [64 sl][12 t][4 c] bf16
  char* twb = smem + 6144;

  const int blk = blockIdx.x, sp = blk >> 2, qq = blk & 3;
  const int tid = threadIdx.x, lane = tid & 63, wave = tid >> 6;

  // ---------------- conv: 1 output channel/thread (256 ch), x staged 4 passes ----
  {
    float* stg = (float*)twb;   // 12288B
    float acc[12];
#pragma unroll
    for (int t = 0; t < 12; ++t) acc[t] = 0.f;
    const int cc_ = tid >> 6, jj = tid & 63;
    const int oc = cc_ * 256 + qq * 64 + jj;
    const float* wrow = conv_w + (size_t)oc * 1024;
#pragma unroll 1
    for (int p = 0; p < 4; ++p) {
      for (int ch2 = tid; ch2 < 3072; ch2 += 256) {
        int e = ch2 / 12, t = ch2 - 12 * e;
        stg[t * 256 + e] = x[(size_t)((p * 256 + e) * 12 + t) * 256 + sp];
      }
      __syncthreads();
      for (int eb = 0; eb < 256; eb += 4) {
        float4 w4 = *(const float4*)(wrow + p * 256 + eb);
#pragma unroll
        for (int t = 0; t < 12; ++t) {
          float4 xv = *(const float4*)&stg[t * 256 + eb];
          acc[t] = fmaf(xv.x, w4.x, acc[t]);
          acc[t] = fmaf(xv.y, w4.y, acc[t]);
          acc[t] = fmaf(xv.z, w4.z, acc[t]);
          acc[t] = fmaf(xv.w, w4.w, acc[t]);
        }
      }
      __syncthreads();
    }
    float sc = bn_g[oc] * rsqrtf(bn_v[oc] + 1e-5f);
    float sh = fmaf(-bn_m[oc], sc, bn_b[oc]);
#pragma unroll
    for (int t = 0; t < 12; ++t) {
      float z = fmaf(acc[t], sc, sh);
      g2[jj * 48 + t * 4 + cc_] = f2b(0.5f * z * (1.f + erff(z * 0.70710678118654752f)));
    }
  }
  __syncthreads();   // g2 read-only; twb free for transformer buffers

  // ---------------- phase 3: 2 seqs in flight per wave, buffers A|B per slot ----
  const int ln = lane & 15, grp = lane >> 4;
  char* Abuf[2] = {twb + wave * 9728, twb + wave * 9728 + 4864};
  char* Bbuf[2] = {Abuf[0] + 2432, Abuf[1] + 2432};
  const u4v* WS = (const u4v*)ws;
#define BT(T) __builtin_bit_cast(s8v, WS[(T) * 64 + lane])
#define STROW(BUF, ROW, COL, VAL) \
  ((unsigned short*)(BUF))[(ROW) * 76 + (COL)] = (VAL)

  float pe[4][4], wic[4][4];
#pragma unroll
  for (int j = 0; j < 4; ++j) {
    int d = j * 16 + ln;
    float freq = expf(-(float)(d & ~1) * (9.210340371976184f / 64.f));
#pragma unroll
    for (int i = 0; i < 4; ++i) {
      float a = freq * (float)(grp * 4 + i);
      pe[i][j] = (d & 1) ? cosf(a) : sinf(a);
    }
#pragma unroll
    for (int c = 0; c < 4; ++c) wic[j][c] = w_in[d * 4 + c];
  }
  float wo4[4];
#pragma unroll
  for (int j = 0; j < 4; ++j) wo4[j] = w_out[j * 16 + ln];
  const float bo0 = b_out[0];

#pragma unroll 1
  for (int itr = 0; itr < 8; ++itr) {
    const int sl0 = wave * 16 + itr * 2;
    f4v v[2][4];

    // ---- h0 (fp32 C-frag) -> A bf16, both seqs ----
    {
      int tb = (grp < 3) ? grp * 4 : 0;
#pragma unroll
      for (int u = 0; u < 2; ++u) {
        const int slu = sl0 + u;
#pragma unroll
        for (int i = 0; i < 4; ++i) {
          uint2 gu = *(const uint2*)(g2 + slu * 48 + (tb + i) * 4);
          float g0 = b2f((unsigned short)(gu.x & 0xffff));
          float g1 = b2f((unsigned short)(gu.x >> 16));
          float g2v = b2f((unsigned short)(gu.y & 0xffff));
          float g3 = b2f((unsigned short)(gu.y >> 16));
#pragma unroll
          for (int j = 0; j < 4; ++j)
            v[u][j][i] = fmaf(g0, wic[j][0], fmaf(g1, wic[j][1],
                         fmaf(g2v, wic[j][2], fmaf(g3, wic[j][3], pe[i][j]))));
        }
#pragma unroll
        for (int i = 0; i < 4; ++i)
#pragma unroll
          for (int j = 0; j < 4; ++j)
            STROW(Abuf[u], grp * 4 + i, j * 16 + ln, f2b(v[u][j][i]));
      }
    }

#pragma unroll 1
    for (int l = 0; l < 2; ++l) {
      s4v vfrag[2][4];
      // ---- QKV: h-frags reg-loaded first; Q -> B, K -> A (h dead), V -> regs ----
      {
        s8v a0[2], a1[2];
#pragma unroll
        for (int u = 0; u < 2; ++u) {
          a0[u] = *(const s8v*)(Abuf[u] + ln * 152 + grp * 16);
          a1[u] = *(const s8v*)(Abuf[u] + ln * 152 + 64 + grp * 16);
        }
#pragma unroll
        for (int j = 0; j < 12; ++j) {
          float bb = qkv_b[l * 192 + j * 16 + ln];
#pragma unroll
          for (int u = 0; u < 2; ++u) {
            f4v c = {bb, bb, bb, bb};
            c = MFMA32(a0[u], BT(l * 24 + j), c);
            c = MFMA32(a1[u], BT(l * 24 + 12 + j), c);
            if (j < 4) {
#pragma unroll
              for (int i = 0; i < 4; ++i)
                STROW(Bbuf[u], grp * 4 + i, j * 16 + ln, f2b(c[i]));
            } else if (j < 8) {
#pragma unroll
              for (int i = 0; i < 4; ++i)
                STROW(Abuf[u], grp * 4 + i, (j - 4) * 16 + ln, f2b(c[i]));
            } else {
              s4v pv;
              pv[0] = (short)f2b(c[0]); pv[1] = (short)f2b(c[1]);
              pv[2] = (short)f2b(c[2]); pv[3] = (short)f2b(c[3]);
              vfrag[u][j - 8] = pv;
            }
          }
        }
      }
      // ---- attention: S^T = mfma(K,Q); O overwrites dead Q tile in B ----
      {
        const f4v z4 = {0.f, 0.f, 0.f, 0.f};
#pragma unroll
        for (int hh = 0; hh < 4; ++hh) {
#pragma unroll
          for (int u = 0; u < 2; ++u) {
            s4v aK = *(const s4v*)(Abuf[u] + ln * 152 + hh * 32 + grp * 8);
            s4v bQ = *(const s4v*)(Bbuf[u] + ln * 152 + hh * 32 + grp * 8);
            f4v sc = MFMA16(aK, bQ, z4);   // lane: score(q=ln, k=grp*4+i)
            float e0, e1, e2, e3;
            if (grp == 3) { e0 = e1 = e2 = e3 = 0.f; }
            else {
              e0 = __expf(sc[0] * 0.25f); e1 = __expf(sc[1] * 0.25f);
              e2 = __expf(sc[2] * 0.25f); e3 = __expf(sc[3] * 0.25f);
            }
            float sm = (e0 + e1) + (e2 + e3);
            sm += __shfl_xor(sm, 16);
            sm += __shfl_xor(sm, 32);
            float inv = 1.f / sm;
            s4v aP;
            aP[0] = (short)f2b(e0 * inv); aP[1] = (short)f2b(e1 * inv);
            aP[2] = (short)f2b(e2 * inv); aP[3] = (short)f2b(e3 * inv);
            f4v o4 = MFMA16(aP, vfrag[u][hh], z4);
#pragma unroll
            for (int i = 0; i < 4; ++i)
              STROW(Bbuf[u], grp * 4 + i, hh * 16 + ln, f2b(o4[i]));
          }
        }
      }
      // ---- O-proj (O in B) + bias folded into residual v ----
      {
        s8v a0[2], a1[2];
#pragma unroll
        for (int u = 0; u < 2; ++u) {
          a0[u] = *(const s8v*)(Bbuf[u] + ln * 152 + grp * 16);
          a1[u] = *(const s8v*)(Bbuf[u] + ln * 152 + 64 + grp * 16);
        }
#pragma unroll
        for (int j = 0; j < 4; ++j) {
          float bb = ob[l * 64 + j * 16 + ln];
          f4v bb4 = {bb, bb, bb, bb};
#pragma unroll
          for (int u = 0; u < 2; ++u) {
            v[u][j] += bb4;
            v[u][j] = MFMA32(a0[u], BT(48 + l * 8 + j), v[u][j]);
            v[u][j] = MFMA32(a1[u], BT(48 + l * 8 + 4 + j), v[u][j]);
          }
        }
      }
      // ---- LN1 -> A ----
      {
        const float* gp = ln1_g + l * 64;
        const float* bp = ln1_b + l * 64;
        float gg[4], bbv[4];
#pragma unroll
        for (int j = 0; j < 4; ++j) { gg[j] = gp[j * 16 + ln]; bbv[j] = bp[j * 16 + ln]; }
#pragma unroll
        for (int i = 0; i < 4; ++i) {
#pragma unroll
          for (int u = 0; u < 2; ++u) {
            float sm = v[u][0][i] + v[u][1][i] + v[u][2][i] + v[u][3][i];
            sm += __shfl_xor(sm, 1); sm += __shfl_xor(sm, 2);
            sm += __shfl_xor(sm, 4); sm += __shfl_xor(sm, 8);
            float mean = sm * 0.015625f;
            float q = 0.f;
#pragma unroll
            for (int j = 0; j < 4; ++j) { float d = v[u][j][i] - mean; q = fmaf(d, d, q); }
            q += __shfl_xor(q, 1); q += __shfl_xor(q, 2);
            q += __shfl_xor(q, 4); q += __shfl_xor(q, 8);
            float rs = rsqrtf(q * 0.015625f + 1e-5f);
#pragma unroll
            for (int j = 0; j < 4; ++j) {
              float nv = fmaf((v[u][j][i] - mean) * rs, gg[j], bbv[j]);
              v[u][j][i] = nv;
              STROW(Abuf[u], grp * 4 + i, j * 16 + ln, f2b(nv));
            }
          }
        }
      }
      // ---- FF: 4 chunks of 64 ff-dims through B (stride 68 ush) ----
      {
        s8v ha0[2], ha1[2];
#pragma unroll
        for (int u = 0; u < 2; ++u) {
          ha0[u] = *(const s8v*)(Abuf[u] + ln * 152 + grp * 16);
          ha1[u] = *(const s8v*)(Abuf[u] + ln * 152 + 64 + grp * 16);
        }
#pragma unroll
        for (int j = 0; j < 4; ++j) {
          float bb = ff2_b[l * 64 + j * 16 + ln];
          f4v bb4 = {bb, bb, bb, bb};
#pragma unroll
          for (int u = 0; u < 2; ++u) v[u][j] += bb4;
        }
#pragma unroll
        for (int c4i = 0; c4i < 4; ++c4i) {
#pragma unroll
          for (int jj4 = 0; jj4 < 4; ++jj4) {
            int jt = c4i * 4 + jj4;
            float bb = ff1_b[l * 256 + jt * 16 + ln];
#pragma unroll
            for (int u = 0; u < 2; ++u) {
              f4v c = {bb, bb, bb, bb};
              c = MFMA32(ha0[u], BT(64 + l * 32 + jt), c);
              c = MFMA32(ha1[u], BT(64 + l * 32 + 16 + jt), c);
#pragma unroll
              for (int i = 0; i < 4; ++i)
                ((unsigned short*)Bbuf[u])[(grp * 4 + i) * 68 + jj4 * 16 + ln] =
                    f2b(fmaxf(c[i], 0.f));
            }
          }
#pragma unroll
          for (int g = 0; g < 2; ++g) {
            int kkg = c4i * 2 + g;
#pragma unroll
            for (int u = 0; u < 2; ++u) {
              s8v fa = *(const s8v*)(Bbuf[u] + ln * 136 + g * 64 + grp * 16);
              v[u][0] = MFMA32(fa, BT(128 + l * 32 + kkg * 4 + 0), v[u][0]);
              v[u][1] = MFMA32(fa, BT(128 + l * 32 + kkg * 4 + 1), v[u][1]);
              v[u][2] = MFMA32(fa, BT(128 + l * 32 + kkg * 4 + 2), v[u][2]);
              v[u][3] = MFMA32(fa, BT(128 + l * 32 + kkg * 4 + 3), v[u][3]);
            }
          }
        }
      }
      // ---- LN2 (store to A only if another layer follows) ----
      {
        const float* gp = ln2_g + l * 64;
        const float* bp = ln2_b + l * 64;
        float gg[4], bbv[4];
#pragma unroll
        for (int j = 0; j < 4; ++j) { gg[j] = gp[j * 16 + ln]; bbv[j] = bp[j * 16 + ln]; }
#pragma unroll
        for (int i = 0; i < 4; ++i) {
#pragma unroll
          for (int u = 0; u < 2; ++u) {
            float sm = v[u][0][i] + v[u][1][i] + v[u][2][i] + v[u][3][i];
            sm += __shfl_xor(sm, 1); sm += __shfl_xor(sm, 2);
            sm += __shfl_xor(sm, 4); sm += __shfl_xor(sm, 8);
            float mean = sm * 0.015625f;
            float q = 0.f;
#pragma unroll
            for (int j = 0; j < 4; ++j) { float d = v[u][j][i] - mean; q = fmaf(d, d, q); }
            q += __shfl_xor(q, 1); q += __shfl_xor(q, 2);
            q += __shfl_xor(q, 4); q += __shfl_xor(q, 8);
            float rs = rsqrtf(q * 0.015625f + 1e-5f);
#pragma unroll
            for (int j = 0; j < 4; ++j) {
              float nv = fmaf((v[u][j][i] - mean) * rs, gg[j], bbv[j]);
              v[u][j][i] = nv;
              if (l == 0) STROW(Abuf[u], grp * 4 + i, j * 16 + ln, f2b(nv));
            }
          }
        }
      }
    } // layer

    // ---- head: mean over t, dot w_out, sigmoid (both seqs) ----
#pragma unroll
    for (int u = 0; u < 2; ++u) {
      float cs[4];
#pragma unroll
      for (int j = 0; j < 4; ++j) {
        float c0 = (grp < 3) ? (v[u][j][0] + v[u][j][1] + v[u][j][2] + v[u][j][3]) : 0.f;
        c0 += __shfl_xor(c0, 16);
        c0 += __shfl_xor(c0, 32);
        cs[j] = c0;
      }
      float dp = cs[0] * wo4[0] + cs[1] * wo4[1] + cs[2] * wo4[2] + cs[3] * wo4[3];
      dp += __shfl_xor(dp, 1);
      dp += __shfl_xor(dp, 2);
      dp += __shfl_xor(dp, 4);
      dp += __shfl_xor(dp, 8);
      if (lane == 0) {
        const int s = qq * 64 + sl0 + u;
        float logit = dp * (1.f / 12.f) + bo0;
        int hf = ((sp >> 4) << 4) | (s >> 4);
        int wf = ((sp & 15) << 4) | (s & 15);
        out[hf * 256 + wf] = 1.f / (1.f + expf(-logit));
      }
    }
  } // seq loop
#undef BT
#undef STROW
}

extern "C" void kernel_launch(void* const* d_in, const int* in_sizes, int n_in,
                              void* d_out, int out_size, void* d_ws, size_t ws_size,
                              hipStream_t stream) {
  (void)in_sizes; (void)n_in; (void)out_size; (void)ws_size;
  wpack<<<48, 256, 0, stream>>>(
      (const float*)d_in[7],  (const float*)d_in[9],
      (const float*)d_in[13], (const float*)d_in[15], (unsigned int*)d_ws);
  prithvi_fused<<<1024, 256, 0, stream>>>(
      (const float*)d_in[0],  (const float*)d_in[1],  (const float*)d_in[2],
      (const float*)d_in[3],  (const float*)d_in[4],  (const float*)d_in[5],
      (const float*)d_in[6],  (const float*)d_in[8],  (const float*)d_in[10],
      (const float*)d_in[11], (const float*)d_in[12], (const float*)d_in[14],
      (const float*)d_in[16], (const float*)d_in[17], (const float*)d_in[18],
      (const float*)d_in[19], (const float*)d_in[20], (const float*)d_ws,
      (float*)d_out);
}

// Round 14
// 1149.410 us; speedup vs baseline: 1.2430x; 1.1554x over previous
//
#include <hip/hip_runtime.h>
#include <math.h>

// R13 = R9 (best, 846us) with interleave widened 2->4 seqs/wave.
// 256-thr blocks (4 waves), grid 512 (half cell = 128 seqs/block).
// LDS = 12KB g + 4 waves x 4 slots x 7296B (R9 slot layout: HB|QB|KB,
// stride-76 rows; F aliases QB, stride 140) = 129KB -> 1 block/CU.
// Rationale: waves/CU empirically pinned at <=8 across R6-R12, so TLP is
// dead; ILP (R8's win) is the axis that pays. 4 independent chains/wave.
// Micro: softmax 1/sm -> rcp (P is bf16-rounded anyway).

typedef __attribute__((ext_vector_type(8))) short s8v;
typedef __attribute__((ext_vector_type(4))) short s4v;
typedef __attribute__((ext_vector_type(4))) float f4v;
typedef __attribute__((ext_vector_type(4))) unsigned int u4v;

#define MFMA32(A, B, C) __builtin_amdgcn_mfma_f32_16x16x32_bf16((A), (B), (C), 0, 0, 0)
#define MFMA16(A, B, C) __builtin_amdgcn_mfma_f32_16x16x16bf16_1k((A), (B), (C), 0, 0, 0)
#define NS 4   // seqs in flight per wave

static __device__ __forceinline__ unsigned short f2b(float f) {
  return __builtin_bit_cast(unsigned short, (__bf16)f);
}
static __device__ __forceinline__ float b2f(unsigned short h) {
  return __builtin_bit_cast(float, ((unsigned)h) << 16);
}

// ---- prologue: pack weights into MFMA B-fragment order (bf16) ----
// tile t: lane l holds B[k = kk*32 + (l>>4)*8 + e][n = j*16 + (l&15)], e=0..7
// bases: qkv l*24 + kk*12 + j | ow 48 + l*8 + kk*4 + j
//        ff1 64 + l*32 + kk*16 + j | ff2 128 + l*32 + kkg*4 + j
__global__ __launch_bounds__(256) void wpack(
    const float* __restrict__ qkv_w, const float* __restrict__ ow,
    const float* __restrict__ ff1_w, const float* __restrict__ ff2_w,
    unsigned int* __restrict__ ws) {
  int gid = blockIdx.x * 256 + threadIdx.x;   // 0..12287
  int tIdx = gid >> 6, lane = gid & 63;
  int ln = lane & 15, grp = lane >> 4;
  const float* src;
  if (tIdx < 48) {
    int l = tIdx / 24, r = tIdx % 24, kk = r / 12, j = r % 12;
    src = qkv_w + l * 12288 + (j * 16 + ln) * 64 + kk * 32 + grp * 8;
  } else if (tIdx < 64) {
    int u = tIdx - 48, l = u / 8, r = u % 8, kk = r / 4, j = r % 4;
    src = ow + l * 4096 + (j * 16 + ln) * 64 + kk * 32 + grp * 8;
  } else if (tIdx < 128) {
    int u = tIdx - 64, l = u / 32, r = u % 32, kk = r / 16, j = r % 16;
    src = ff1_w + l * 16384 + (j * 16 + ln) * 64 + kk * 32 + grp * 8;
  } else {
    int u = tIdx - 128, l = u / 32, r = u % 32, kk = r / 4, j = r % 4;
    src = ff2_w + l * 16384 + (j * 16 + ln) * 256 + kk * 32 + grp * 8;
  }
  unsigned p[4];
#pragma unroll
  for (int e = 0; e < 4; ++e)
    p[e] = (unsigned)f2b(src[2 * e]) | ((unsigned)f2b(src[2 * e + 1]) << 16);
  u4v val = {p[0], p[1], p[2], p[3]};
  *(u4v*)(ws + (size_t)gid * 4) = val;
}

__global__ __launch_bounds__(256) void prithvi_fused(
    const float* __restrict__ x,     const float* __restrict__ conv_w,
    const float* __restrict__ bn_g,  const float* __restrict__ bn_b,
    const float* __restrict__ bn_m,  const float* __restrict__ bn_v,
    const float* __restrict__ w_in,  const float* __restrict__ qkv_b,
    const float* __restrict__ ob,    const float* __restrict__ ln1_g,
    const float* __restrict__ ln1_b, const float* __restrict__ ff1_b,
    const float* __restrict__ ff2_b, const float* __restrict__ ln2_g,
    const float* __restrict__ ln2_b, const float* __restrict__ w_out,
    const float* __restrict__ b_out, const float* __restrict__ ws,
    float* __restrict__ out)
{
  // 12288B g2 + 116736B transformer slots (conv staging 12288B aliases slots)
  __shared__ __align__(16) char smem[129024];
  unsigned short* g2 = (unsigned short*)smem;   // [128 jj][12 t][4 c] bf16
  char* twb = smem + 12288;

  const int blk = blockIdx.x, sp = blk >> 1, bh = blk & 1;
  const int tid = threadIdx.x, lane = tid & 63, wave = tid >> 6;

  // ---------------- conv: 2 oc/thread (this half's 512 ch), x staged 4 passes ----
  {
    float* stg = (float*)twb;   // 12288B
    float acc0[12], acc1[12];
#pragma unroll
    for (int t = 0; t < 12; ++t) { acc0[t] = 0.f; acc1[t] = 0.f; }
    const int c_ = tid >> 7, jj = tid & 127;
    const int oc0 = c_ * 256 + bh * 128 + jj;
    const int oc1 = (c_ + 2) * 256 + bh * 128 + jj;
    const float* w0p = conv_w + (size_t)oc0 * 1024;
    const float* w1p = conv_w + (size_t)oc1 * 1024;
#pragma unroll 1
    for (int p = 0; p < 4; ++p) {
      for (int ch2 = tid; ch2 < 3072; ch2 += 256) {
        int e = ch2 / 12, t = ch2 - 12 * e;
        stg[t * 256 + e] = x[(size_t)((p * 256 + e) * 12 + t) * 256 + sp];
      }
      __syncthreads();
      for (int eb = 0; eb < 256; eb += 4) {
        float4 wa = *(const float4*)(w0p + p * 256 + eb);
        float4 wb = *(const float4*)(w1p + p * 256 + eb);
#pragma unroll
        for (int t = 0; t < 12; ++t) {
          float4 xv = *(const float4*)&stg[t * 256 + eb];
          acc0[t] = fmaf(xv.x, wa.x, acc0[t]);
          acc0[t] = fmaf(xv.y, wa.y, acc0[t]);
          acc0[t] = fmaf(xv.z, wa.z, acc0[t]);
          acc0[t] = fmaf(xv.w, wa.w, acc0[t]);
          acc1[t] = fmaf(xv.x, wb.x, acc1[t]);
          acc1[t] = fmaf(xv.y, wb.y, acc1[t]);
          acc1[t] = fmaf(xv.z, wb.z, acc1[t]);
          acc1[t] = fmaf(xv.w, wb.w, acc1[t]);
        }
      }
      __syncthreads();
    }
    {
      float sc0 = bn_g[oc0] * rsqrtf(bn_v[oc0] + 1e-5f);
      float sh0 = fmaf(-bn_m[oc0], sc0, bn_b[oc0]);
#pragma unroll
      for (int t = 0; t < 12; ++t) {
        float z = fmaf(acc0[t], sc0, sh0);
        g2[jj * 48 + t * 4 + c_] = f2b(0.5f * z * (1.f + erff(z * 0.70710678118654752f)));
      }
      float sc1 = bn_g[oc1] * rsqrtf(bn_v[oc1] + 1e-5f);
      float sh1 = fmaf(-bn_m[oc1], sc1, bn_b[oc1]);
#pragma unroll
      for (int t = 0; t < 12; ++t) {
        float z = fmaf(acc1[t], sc1, sh1);
        g2[jj * 48 + t * 4 + c_ + 2] = f2b(0.5f * z * (1.f + erff(z * 0.70710678118654752f)));
      }
    }
  }
  __syncthreads();   // g2 read-only; twb free for transformer slots

  // ---------------- phase 3: NS seqs in flight per wave ----------------
  const int ln = lane & 15, grp = lane >> 4;
  char* HB[NS];
  char* QB[NS];
  char* KB[NS];
#pragma unroll
  for (int u = 0; u < NS; ++u) {
    HB[u] = twb + wave * (NS * 7296) + u * 7296;
    QB[u] = HB[u] + 2432;
    KB[u] = HB[u] + 4864;
  }
  const u4v* WS = (const u4v*)ws;
#define BT(T) __builtin_bit_cast(s8v, WS[(T) * 64 + lane])
#define STROW(BUF, ROW, COL, VAL) \
  ((unsigned short*)(BUF))[(ROW) * 76 + (COL)] = (VAL)

  float pe[4][4], wic[4][4];
#pragma unroll
  for (int j = 0; j < 4; ++j) {
    int d = j * 16 + ln;
    float freq = expf(-(float)(d & ~1) * (9.210340371976184f / 64.f));
#pragma unroll
    for (int i = 0; i < 4; ++i) {
      float a = freq * (float)(grp * 4 + i);
      pe[i][j] = (d & 1) ? cosf(a) : sinf(a);
    }
#pragma unroll
    for (int c = 0; c < 4; ++c) wic[j][c] = w_in[d * 4 + c];
  }
  float wo4[4];
#pragma unroll
  for (int j = 0; j < 4; ++j) wo4[j] = w_out[j * 16 + ln];
  const float bo0 = b_out[0];

#pragma unroll 1
  for (int itr = 0; itr < 8; ++itr) {
    const int sl0 = wave * 32 + itr * NS;   // local seq base (0..127)
    f4v v[NS][4];

    // ---- h0 (fp32 C-frag) -> HB bf16, all seqs ----
    {
      int tb = (grp < 3) ? grp * 4 : 0;
#pragma unroll
      for (int u = 0; u < NS; ++u) {
        const int slu = sl0 + u;
#pragma unroll
        for (int i = 0; i < 4; ++i) {
          uint2 gu = *(const uint2*)(g2 + slu * 48 + (tb + i) * 4);
          float g0 = b2f((unsigned short)(gu.x & 0xffff));
          float g1 = b2f((unsigned short)(gu.x >> 16));
          float g2v = b2f((unsigned short)(gu.y & 0xffff));
          float g3 = b2f((unsigned short)(gu.y >> 16));
#pragma unroll
          for (int j = 0; j < 4; ++j)
            v[u][j][i] = fmaf(g0, wic[j][0], fmaf(g1, wic[j][1],
                         fmaf(g2v, wic[j][2], fmaf(g3, wic[j][3], pe[i][j]))));
        }
#pragma unroll
        for (int i = 0; i < 4; ++i)
#pragma unroll
          for (int j = 0; j < 4; ++j)
            STROW(HB[u], grp * 4 + i, j * 16 + ln, f2b(v[u][j][i]));
      }
    }

#pragma unroll 1
    for (int l = 0; l < 2; ++l) {
      s4v vfrag[NS][4];
      // ---- QKV: Q -> QB, K -> KB, V -> regs (C-frag == PV B-frag) ----
      {
        s8v a0[NS], a1[NS];
#pragma unroll
        for (int u = 0; u < NS; ++u) {
          a0[u] = *(const s8v*)(HB[u] + ln * 152 + grp * 16);
          a1[u] = *(const s8v*)(HB[u] + ln * 152 + 64 + grp * 16);
        }
#pragma unroll
        for (int j = 0; j < 12; ++j) {
          float bb = qkv_b[l * 192 + j * 16 + ln];
#pragma unroll
          for (int u = 0; u < NS; ++u) {
            f4v c = {bb, bb, bb, bb};
            c = MFMA32(a0[u], BT(l * 24 + j), c);
            c = MFMA32(a1[u], BT(l * 24 + 12 + j), c);
            if (j < 4) {
#pragma unroll
              for (int i = 0; i < 4; ++i)
                STROW(QB[u], grp * 4 + i, j * 16 + ln, f2b(c[i]));
            } else if (j < 8) {
#pragma unroll
              for (int i = 0; i < 4; ++i)
                STROW(KB[u], grp * 4 + i, (j - 4) * 16 + ln, f2b(c[i]));
            } else {
              s4v pv;
              pv[0] = (short)f2b(c[0]); pv[1] = (short)f2b(c[1]);
              pv[2] = (short)f2b(c[2]); pv[3] = (short)f2b(c[3]);
              vfrag[u][j - 8] = pv;
            }
          }
        }
      }
      // ---- attention: S^T = mfma(K,Q); O -> KB (K dead per head) ----
      {
        const f4v z4 = {0.f, 0.f, 0.f, 0.f};
#pragma unroll
        for (int hh = 0; hh < 4; ++hh) {
#pragma unroll
          for (int u = 0; u < NS; ++u) {
            s4v aK = *(const s4v*)(KB[u] + ln * 152 + hh * 32 + grp * 8);
            s4v bQ = *(const s4v*)(QB[u] + ln * 152 + hh * 32 + grp * 8);
            f4v sc = MFMA16(aK, bQ, z4);   // lane: score(q=ln, k=grp*4+i)
            float e0, e1, e2, e3;
            if (grp == 3) { e0 = e1 = e2 = e3 = 0.f; }
            else {
              e0 = __expf(sc[0] * 0.25f); e1 = __expf(sc[1] * 0.25f);
              e2 = __expf(sc[2] * 0.25f); e3 = __expf(sc[3] * 0.25f);
            }
            float sm = (e0 + e1) + (e2 + e3);
            sm += __shfl_xor(sm, 16);
            sm += __shfl_xor(sm, 32);
            float inv = __builtin_amdgcn_rcpf(sm);
            s4v aP;
            aP[0] = (short)f2b(e0 * inv); aP[1] = (short)f2b(e1 * inv);
            aP[2] = (short)f2b(e2 * inv); aP[3] = (short)f2b(e3 * inv);
            f4v o4 = MFMA16(aP, vfrag[u][hh], z4);
#pragma unroll
            for (int i = 0; i < 4; ++i)
              STROW(KB[u], grp * 4 + i, hh * 16 + ln, f2b(o4[i]));
          }
        }
      }
      // ---- O-proj (O in KB) + bias folded into residual v ----
      {
        s8v a0[NS], a1[NS];
#pragma unroll
        for (int u = 0; u < NS; ++u) {
          a0[u] = *(const s8v*)(KB[u] + ln * 152 + grp * 16);
          a1[u] = *(const s8v*)(KB[u] + ln * 152 + 64 + grp * 16);
        }
#pragma unroll
        for (int j = 0; j < 4; ++j) {
          float bb = ob[l * 64 + j * 16 + ln];
          f4v bb4 = {bb, bb, bb, bb};
#pragma unroll
          for (int u = 0; u < NS; ++u) {
            v[u][j] += bb4;
            v[u][j] = MFMA32(a0[u], BT(48 + l * 8 + j), v[u][j]);
            v[u][j] = MFMA32(a1[u], BT(48 + l * 8 + 4 + j), v[u][j]);
          }
        }
      }
      // ---- LN1 -> HB ----
      {
        const float* gp = ln1_g + l * 64;
        const float* bp = ln1_b + l * 64;
        float gg[4], bbv[4];
#pragma unroll
        for (int j = 0; j < 4; ++j) { gg[j] = gp[j * 16 + ln]; bbv[j] = bp[j * 16 + ln]; }
#pragma unroll
        for (int i = 0; i < 4; ++i) {
#pragma unroll
          for (int u = 0; u < NS; ++u) {
            float sm = v[u][0][i] + v[u][1][i] + v[u][2][i] + v[u][3][i];
            sm += __shfl_xor(sm, 1); sm += __shfl_xor(sm, 2);
            sm += __shfl_xor(sm, 4); sm += __shfl_xor(sm, 8);
            float mean = sm * 0.015625f;
            float q = 0.f;
#pragma unroll
            for (int j = 0; j < 4; ++j) { float d = v[u][j][i] - mean; q = fmaf(d, d, q); }
            q += __shfl_xor(q, 1); q += __shfl_xor(q, 2);
            q += __shfl_xor(q, 4); q += __shfl_xor(q, 8);
            float rs = rsqrtf(q * 0.015625f + 1e-5f);
#pragma unroll
            for (int j = 0; j < 4; ++j) {
              float nv = fmaf((v[u][j][i] - mean) * rs, gg[j], bbv[j]);
              v[u][j][i] = nv;
              STROW(HB[u], grp * 4 + i, j * 16 + ln, f2b(nv));
            }
          }
        }
      }
      // ---- FF: 2 halves of 128 ff-dims through F (aliases QB+KB, stride 140) ----
      {
        s8v ha0[NS], ha1[NS];
#pragma unroll
        for (int u = 0; u < NS; ++u) {
          ha0[u] = *(const s8v*)(HB[u] + ln * 152 + grp * 16);
          ha1[u] = *(const s8v*)(HB[u] + ln * 152 + 64 + grp * 16);
        }
#pragma unroll
        for (int j = 0; j < 4; ++j) {
          float bb = ff2_b[l * 64 + j * 16 + ln];
          f4v bb4 = {bb, bb, bb, bb};
#pragma unroll
          for (int u = 0; u < NS; ++u) v[u][j] += bb4;
        }
#pragma unroll
        for (int fh = 0; fh < 2; ++fh) {
#pragma unroll
          for (int j8 = 0; j8 < 8; ++j8) {
            int jt = fh * 8 + j8;
            float bb = ff1_b[l * 256 + jt * 16 + ln];
#pragma unroll
            for (int u = 0; u < NS; ++u) {
              f4v c = {bb, bb, bb, bb};
              c = MFMA32(ha0[u], BT(64 + l * 32 + jt), c);
              c = MFMA32(ha1[u], BT(64 + l * 32 + 16 + jt), c);
#pragma unroll
              for (int i = 0; i < 4; ++i)
                ((unsigned short*)QB[u])[(grp * 4 + i) * 140 + j8 * 16 + ln] =
                    f2b(fmaxf(c[i], 0.f));
            }
          }
#pragma unroll
          for (int kk2 = 0; kk2 < 4; ++kk2) {
            int kkg = fh * 4 + kk2;
#pragma unroll
            for (int u = 0; u < NS; ++u) {
              s8v fa = *(const s8v*)(QB[u] + ln * 280 + kk2 * 64 + grp * 16);
              v[u][0] = MFMA32(fa, BT(128 + l * 32 + kkg * 4 + 0), v[u][0]);
              v[u][1] = MFMA32(fa, BT(128 + l * 32 + kkg * 4 + 1), v[u][1]);
              v[u][2] = MFMA32(fa, BT(128 + l * 32 + kkg * 4 + 2), v[u][2]);
              v[u][3] = MFMA32(fa, BT(128 + l * 32 + kkg * 4 + 3), v[u][3]);
            }
          }
        }
      }
      // ---- LN2 (store to HB only if another layer follows) ----
      {
        const float* gp = ln2_g + l * 64;
        const float* bp = ln2_b + l * 64;
        float gg[4], bbv[4];
#pragma unroll
        for (int j = 0; j < 4; ++j) { gg[j] = gp[j * 16 + ln]; bbv[j] = bp[j * 16 + ln]; }
#pragma unroll
        for (int i = 0; i < 4; ++i) {
#pragma unroll
          for (int u = 0; u < NS; ++u) {
            float sm = v[u][0][i] + v[u][1][i] + v[u][2][i] + v[u][3][i];
            sm += __shfl_xor(sm, 1); sm += __shfl_xor(sm, 2);
            sm += __shfl_xor(sm, 4); sm += __shfl_xor(sm, 8);
            float mean = sm * 0.015625f;
            float q = 0.f;
#pragma unroll
            for (int j = 0; j < 4; ++j) { float d = v[u][j][i] - mean; q = fmaf(d, d, q); }
            q += __shfl_xor(q, 1); q += __shfl_xor(q, 2);
            q += __shfl_xor(q, 4); q += __shfl_xor(q, 8);
            float rs = rsqrtf(q * 0.015625f + 1e-5f);
#pragma unroll
            for (int j = 0; j < 4; ++j) {
              float nv = fmaf((v[u][j][i] - mean) * rs, gg[j], bbv[j]);
              v[u][j][i] = nv;
              if (l == 0) STROW(HB[u], grp * 4 + i, j * 16 + ln, f2b(nv));
            }
          }
        }
      }
    } // layer

    // ---- head: mean over t, dot w_out, sigmoid (all seqs) ----
#pragma unroll
    for (int u = 0; u < NS; ++u) {
      float cs[4];
#pragma unroll
      for (int j = 0; j < 4; ++j) {
        float c0 = (grp < 3) ? (v[u][j][0] + v[u][j][1] + v[u][j][2] + v[u][j][3]) : 0.f;
        c0 += __shfl_xor(c0, 16);
        c0 += __shfl_xor(c0, 32);
        cs[j] = c0;
      }
      float dp = cs[0] * wo4[0] + cs[1] * wo4[1] + cs[2] * wo4[2] + cs[3] * wo4[3];
      dp += __shfl_xor(dp, 1);
      dp += __shfl_xor(dp, 2);
      dp += __shfl_xor(dp, 4);
      dp += __shfl_xor(dp, 8);
      if (lane == 0) {
        const int s = bh * 128 + sl0 + u;
        float logit = dp * (1.f / 12.f) + bo0;
        int hf = ((sp >> 4) << 4) | (s >> 4);
        int wf = ((sp & 15) << 4) | (s & 15);
        out[hf * 256 + wf] = 1.f / (1.f + expf(-logit));
      }
    }
  } // seq loop
#undef BT
#undef STROW
}

extern "C" void kernel_launch(void* const* d_in, const int* in_sizes, int n_in,
                              void* d_out, int out_size, void* d_ws, size_t ws_size,
                              hipStream_t stream) {
  (void)in_sizes; (void)n_in; (void)out_size; (void)ws_size;
  wpack<<<48, 256, 0, stream>>>(
      (const float*)d_in[7],  (const float*)d_in[9],
      (const float*)d_in[13], (const float*)d_in[15], (unsigned int*)d_ws);
  prithvi_fused<<<512, 256, 0, stream>>>(
      (const float*)d_in[0],  (const float*)d_in[1],  (const float*)d_in[2],
      (const float*)d_in[3],  (const float*)d_in[4],  (const float*)d_in[5],
      (const float*)d_in[6],  (const float*)d_in[8],  (const float*)d_in[10],
      (const float*)d_in[11], (const float*)d_in[12], (const float*)d_in[14],
      (const float*)d_in[16], (const float*)d_in[17], (const float*)d_in[18],
      (const float*)d_in[19], (const float*)d_in[20], (const float*)d_ws,
      (float*)d_out);
}

// Round 15
// 763.553 us; speedup vs baseline: 1.8712x; 1.5053x over previous
//
#include <hip/hip_runtime.h>
#include <math.h>

// R14 = R9 structure at 1024-thr blocks (16 waves/CU, 4/SIMD), NS=1.
// Evidence: blocks/CU pinned at 1 in all configs; 8 waves (R9,846us) beat
// 4 waves + deep ILP (R13,1149us) at equal seqs-in-flight -> wave-TLP is
// the axis. LDS = 24576 g + 16x7296 slots = 141312 (same as R9). Grid 256,
// conv 1 ch/thread, 16 seqs/wave sequentially.

typedef __attribute__((ext_vector_type(8))) short s8v;
typedef __attribute__((ext_vector_type(4))) short s4v;
typedef __attribute__((ext_vector_type(4))) float f4v;
typedef __attribute__((ext_vector_type(4))) unsigned int u4v;

#define MFMA32(A, B, C) __builtin_amdgcn_mfma_f32_16x16x32_bf16((A), (B), (C), 0, 0, 0)
#define MFMA16(A, B, C) __builtin_amdgcn_mfma_f32_16x16x16bf16_1k((A), (B), (C), 0, 0, 0)

static __device__ __forceinline__ unsigned short f2b(float f) {
  return __builtin_bit_cast(unsigned short, (__bf16)f);
}
static __device__ __forceinline__ float b2f(unsigned short h) {
  return __builtin_bit_cast(float, ((unsigned)h) << 16);
}

// ---- prologue: pack weights into MFMA B-fragment order (bf16) ----
// tile t: lane l holds B[k = kk*32 + (l>>4)*8 + e][n = j*16 + (l&15)], e=0..7
// bases: qkv l*24 + kk*12 + j | ow 48 + l*8 + kk*4 + j
//        ff1 64 + l*32 + kk*16 + j | ff2 128 + l*32 + kkg*4 + j
__global__ __launch_bounds__(256) void wpack(
    const float* __restrict__ qkv_w, const float* __restrict__ ow,
    const float* __restrict__ ff1_w, const float* __restrict__ ff2_w,
    unsigned int* __restrict__ ws) {
  int gid = blockIdx.x * 256 + threadIdx.x;   // 0..12287
  int tIdx = gid >> 6, lane = gid & 63;
  int ln = lane & 15, grp = lane >> 4;
  const float* src;
  if (tIdx < 48) {
    int l = tIdx / 24, r = tIdx % 24, kk = r / 12, j = r % 12;
    src = qkv_w + l * 12288 + (j * 16 + ln) * 64 + kk * 32 + grp * 8;
  } else if (tIdx < 64) {
    int u = tIdx - 48, l = u / 8, r = u % 8, kk = r / 4, j = r % 4;
    src = ow + l * 4096 + (j * 16 + ln) * 64 + kk * 32 + grp * 8;
  } else if (tIdx < 128) {
    int u = tIdx - 64, l = u / 32, r = u % 32, kk = r / 16, j = r % 16;
    src = ff1_w + l * 16384 + (j * 16 + ln) * 64 + kk * 32 + grp * 8;
  } else {
    int u = tIdx - 128, l = u / 32, r = u % 32, kk = r / 4, j = r % 4;
    src = ff2_w + l * 16384 + (j * 16 + ln) * 256 + kk * 32 + grp * 8;
  }
  unsigned p[4];
#pragma unroll
  for (int e = 0; e < 4; ++e)
    p[e] = (unsigned)f2b(src[2 * e]) | ((unsigned)f2b(src[2 * e + 1]) << 16);
  u4v val = {p[0], p[1], p[2], p[3]};
  *(u4v*)(ws + (size_t)gid * 4) = val;
}

__global__ __launch_bounds__(1024) void prithvi_fused(
    const float* __restrict__ x,     const float* __restrict__ conv_w,
    const float* __restrict__ bn_g,  const float* __restrict__ bn_b,
    const float* __restrict__ bn_m,  const float* __restrict__ bn_v,
    const float* __restrict__ w_in,  const float* __restrict__ qkv_b,
    const float* __restrict__ ob,    const float* __restrict__ ln1_g,
    const float* __restrict__ ln1_b, const float* __restrict__ ff1_b,
    const float* __restrict__ ff2_b, const float* __restrict__ ln2_g,
    const float* __restrict__ ln2_b, const float* __restrict__ w_out,
    const float* __restrict__ b_out, const float* __restrict__ ws,
    float* __restrict__ out)
{
  // 24576B g2 + 16 x 7296B wave slots (conv staging 12288B aliases slots)
  __shared__ __align__(16) char smem[141312];
  unsigned short* g2 = (unsigned short*)smem;   // [256 sl][12 t][4 c] bf16
  char* twb = smem + 24576;

  const int sp = blockIdx.x;
  const int tid = threadIdx.x, lane = tid & 63, wave = tid >> 6;

  // ---------------- conv: 1 output channel/thread, x staged 4 passes ----
  {
    float* stg = (float*)twb;   // 12288B
    float acc[12];
#pragma unroll
    for (int t = 0; t < 12; ++t) acc[t] = 0.f;
    const int c_ = tid >> 8, jj = tid & 255;
    const int oc = c_ * 256 + jj;
    const float* wrow = conv_w + (size_t)oc * 1024;
#pragma unroll 1
    for (int p = 0; p < 4; ++p) {
      for (int ch2 = tid; ch2 < 3072; ch2 += 1024) {
        int e = ch2 / 12, t = ch2 - 12 * e;
        stg[t * 256 + e] = x[(size_t)((p * 256 + e) * 12 + t) * 256 + sp];
      }
      __syncthreads();
      for (int eb = 0; eb < 256; eb += 4) {
        float4 w4 = *(const float4*)(wrow + p * 256 + eb);
#pragma unroll
        for (int t = 0; t < 12; ++t) {
          float4 xv = *(const float4*)&stg[t * 256 + eb];
          acc[t] = fmaf(xv.x, w4.x, acc[t]);
          acc[t] = fmaf(xv.y, w4.y, acc[t]);
          acc[t] = fmaf(xv.z, w4.z, acc[t]);
          acc[t] = fmaf(xv.w, w4.w, acc[t]);
        }
      }
      __syncthreads();
    }
    float sc = bn_g[oc] * rsqrtf(bn_v[oc] + 1e-5f);
    float sh = fmaf(-bn_m[oc], sc, bn_b[oc]);
#pragma unroll
    for (int t = 0; t < 12; ++t) {
      float z = fmaf(acc[t], sc, sh);
      g2[jj * 48 + t * 4 + c_] = f2b(0.5f * z * (1.f + erff(z * 0.70710678118654752f)));
    }
  }
  __syncthreads();   // g2 read-only; twb free for transformer slots

  // ---------------- phase 3: 1 seq at a time, 16 waves ----------------
  const int ln = lane & 15, grp = lane >> 4;
  char* HB = twb + wave * 7296;
  char* QB = HB + 2432;
  char* KB = HB + 4864;
  const u4v* WS = (const u4v*)ws;
#define BT(T) __builtin_bit_cast(s8v, WS[(T) * 64 + lane])
#define STROW(BUF, ROW, COL, VAL) \
  ((unsigned short*)(BUF))[(ROW) * 76 + (COL)] = (VAL)

  float pe[4][4], wic[4][4];
#pragma unroll
  for (int j = 0; j < 4; ++j) {
    int d = j * 16 + ln;
    float freq = expf(-(float)(d & ~1) * (9.210340371976184f / 64.f));
#pragma unroll
    for (int i = 0; i < 4; ++i) {
      float a = freq * (float)(grp * 4 + i);
      pe[i][j] = (d & 1) ? cosf(a) : sinf(a);
    }
#pragma unroll
    for (int c = 0; c < 4; ++c) wic[j][c] = w_in[d * 4 + c];
  }
  float wo4[4];
#pragma unroll
  for (int j = 0; j < 4; ++j) wo4[j] = w_out[j * 16 + ln];
  const float bo0 = b_out[0];

#pragma unroll 1
  for (int itr = 0; itr < 16; ++itr) {
    const int sl = wave * 16 + itr;   // seq 0..255
    f4v v[4];

    // ---- h0 (fp32 C-frag) -> HB bf16 ----
    {
      int tb = (grp < 3) ? grp * 4 : 0;
#pragma unroll
      for (int i = 0; i < 4; ++i) {
        uint2 gu = *(const uint2*)(g2 + sl * 48 + (tb + i) * 4);
        float g0 = b2f((unsigned short)(gu.x & 0xffff));
        float g1 = b2f((unsigned short)(gu.x >> 16));
        float g2v = b2f((unsigned short)(gu.y & 0xffff));
        float g3 = b2f((unsigned short)(gu.y >> 16));
#pragma unroll
        for (int j = 0; j < 4; ++j)
          v[j][i] = fmaf(g0, wic[j][0], fmaf(g1, wic[j][1],
                    fmaf(g2v, wic[j][2], fmaf(g3, wic[j][3], pe[i][j]))));
      }
#pragma unroll
      for (int i = 0; i < 4; ++i)
#pragma unroll
        for (int j = 0; j < 4; ++j)
          STROW(HB, grp * 4 + i, j * 16 + ln, f2b(v[j][i]));
    }

#pragma unroll 1
    for (int l = 0; l < 2; ++l) {
      s4v vfrag[4];
      // ---- QKV: Q -> QB, K -> KB, V -> regs (C-frag == PV B-frag) ----
      {
        s8v a0 = *(const s8v*)(HB + ln * 152 + grp * 16);
        s8v a1 = *(const s8v*)(HB + ln * 152 + 64 + grp * 16);
#pragma unroll
        for (int j = 0; j < 12; ++j) {
          float bb = qkv_b[l * 192 + j * 16 + ln];
          f4v c = {bb, bb, bb, bb};
          c = MFMA32(a0, BT(l * 24 + j), c);
          c = MFMA32(a1, BT(l * 24 + 12 + j), c);
          if (j < 4) {
#pragma unroll
            for (int i = 0; i < 4; ++i)
              STROW(QB, grp * 4 + i, j * 16 + ln, f2b(c[i]));
          } else if (j < 8) {
#pragma unroll
            for (int i = 0; i < 4; ++i)
              STROW(KB, grp * 4 + i, (j - 4) * 16 + ln, f2b(c[i]));
          } else {
            s4v pv;
            pv[0] = (short)f2b(c[0]); pv[1] = (short)f2b(c[1]);
            pv[2] = (short)f2b(c[2]); pv[3] = (short)f2b(c[3]);
            vfrag[j - 8] = pv;
          }
        }
      }
      // ---- attention: S^T = mfma(K,Q); O -> KB (K dead per head) ----
      {
        const f4v z4 = {0.f, 0.f, 0.f, 0.f};
#pragma unroll
        for (int hh = 0; hh < 4; ++hh) {
          s4v aK = *(const s4v*)(KB + ln * 152 + hh * 32 + grp * 8);
          s4v bQ = *(const s4v*)(QB + ln * 152 + hh * 32 + grp * 8);
          f4v sc = MFMA16(aK, bQ, z4);   // lane: score(q=ln, k=grp*4+i)
          float e0, e1, e2, e3;
          if (grp == 3) { e0 = e1 = e2 = e3 = 0.f; }
          else {
            e0 = __expf(sc[0] * 0.25f); e1 = __expf(sc[1] * 0.25f);
            e2 = __expf(sc[2] * 0.25f); e3 = __expf(sc[3] * 0.25f);
          }
          float sm = (e0 + e1) + (e2 + e3);
          sm += __shfl_xor(sm, 16);
          sm += __shfl_xor(sm, 32);
          float inv = __builtin_amdgcn_rcpf(sm);
          s4v aP;
          aP[0] = (short)f2b(e0 * inv); aP[1] = (short)f2b(e1 * inv);
          aP[2] = (short)f2b(e2 * inv); aP[3] = (short)f2b(e3 * inv);
          f4v o4 = MFMA16(aP, vfrag[hh], z4);
#pragma unroll
          for (int i = 0; i < 4; ++i)
            STROW(KB, grp * 4 + i, hh * 16 + ln, f2b(o4[i]));
        }
      }
      // ---- O-proj (O in KB) + bias folded into residual v ----
      {
        s8v a0 = *(const s8v*)(KB + ln * 152 + grp * 16);
        s8v a1 = *(const s8v*)(KB + ln * 152 + 64 + grp * 16);
#pragma unroll
        for (int j = 0; j < 4; ++j) {
          float bb = ob[l * 64 + j * 16 + ln];
          f4v bb4 = {bb, bb, bb, bb};
          v[j] += bb4;
          v[j] = MFMA32(a0, BT(48 + l * 8 + j), v[j]);
          v[j] = MFMA32(a1, BT(48 + l * 8 + 4 + j), v[j]);
        }
      }
      // ---- LN1 -> HB ----
      {
        const float* gp = ln1_g + l * 64;
        const float* bp = ln1_b + l * 64;
        float gg[4], bbv[4];
#pragma unroll
        for (int j = 0; j < 4; ++j) { gg[j] = gp[j * 16 + ln]; bbv[j] = bp[j * 16 + ln]; }
#pragma unroll
        for (int i = 0; i < 4; ++i) {
          float sm = v[0][i] + v[1][i] + v[2][i] + v[3][i];
          sm += __shfl_xor(sm, 1); sm += __shfl_xor(sm, 2);
          sm += __shfl_xor(sm, 4); sm += __shfl_xor(sm, 8);
          float mean = sm * 0.015625f;
          float q = 0.f;
#pragma unroll
          for (int j = 0; j < 4; ++j) { float d = v[j][i] - mean; q = fmaf(d, d, q); }
          q += __shfl_xor(q, 1); q += __shfl_xor(q, 2);
          q += __shfl_xor(q, 4); q += __shfl_xor(q, 8);
          float rs = rsqrtf(q * 0.015625f + 1e-5f);
#pragma unroll
          for (int j = 0; j < 4; ++j) {
            float nv = fmaf((v[j][i] - mean) * rs, gg[j], bbv[j]);
            v[j][i] = nv;
            STROW(HB, grp * 4 + i, j * 16 + ln, f2b(nv));
          }
        }
      }
      // ---- FF: 2 halves of 128 ff-dims through F (aliases QB+KB, stride 140) ----
      {
        s8v ha0 = *(const s8v*)(HB + ln * 152 + grp * 16);
        s8v ha1 = *(const s8v*)(HB + ln * 152 + 64 + grp * 16);
#pragma unroll
        for (int j = 0; j < 4; ++j) {
          float bb = ff2_b[l * 64 + j * 16 + ln];
          f4v bb4 = {bb, bb, bb, bb};
          v[j] += bb4;
        }
#pragma unroll
        for (int fh = 0; fh < 2; ++fh) {
#pragma unroll
          for (int j8 = 0; j8 < 8; ++j8) {
            int jt = fh * 8 + j8;
            float bb = ff1_b[l * 256 + jt * 16 + ln];
            f4v c = {bb, bb, bb, bb};
            c = MFMA32(ha0, BT(64 + l * 32 + jt), c);
            c = MFMA32(ha1, BT(64 + l * 32 + 16 + jt), c);
#pragma unroll
            for (int i = 0; i < 4; ++i)
              ((unsigned short*)QB)[(grp * 4 + i) * 140 + j8 * 16 + ln] =
                  f2b(fmaxf(c[i], 0.f));
          }
#pragma unroll
          for (int kk2 = 0; kk2 < 4; ++kk2) {
            int kkg = fh * 4 + kk2;
            s8v fa = *(const s8v*)(QB + ln * 280 + kk2 * 64 + grp * 16);
            v[0] = MFMA32(fa, BT(128 + l * 32 + kkg * 4 + 0), v[0]);
            v[1] = MFMA32(fa, BT(128 + l * 32 + kkg * 4 + 1), v[1]);
            v[2] = MFMA32(fa, BT(128 + l * 32 + kkg * 4 + 2), v[2]);
            v[3] = MFMA32(fa, BT(128 + l * 32 + kkg * 4 + 3), v[3]);
          }
        }
      }
      // ---- LN2 (store to HB only if another layer follows) ----
      {
        const float* gp = ln2_g + l * 64;
        const float* bp = ln2_b + l * 64;
        float gg[4], bbv[4];
#pragma unroll
        for (int j = 0; j < 4; ++j) { gg[j] = gp[j * 16 + ln]; bbv[j] = bp[j * 16 + ln]; }
#pragma unroll
        for (int i = 0; i < 4; ++i) {
          float sm = v[0][i] + v[1][i] + v[2][i] + v[3][i];
          sm += __shfl_xor(sm, 1); sm += __shfl_xor(sm, 2);
          sm += __shfl_xor(sm, 4); sm += __shfl_xor(sm, 8);
          float mean = sm * 0.015625f;
          float q = 0.f;
#pragma unroll
          for (int j = 0; j < 4; ++j) { float d = v[j][i] - mean; q = fmaf(d, d, q); }
          q += __shfl_xor(q, 1); q += __shfl_xor(q, 2);
          q += __shfl_xor(q, 4); q += __shfl_xor(q, 8);
          float rs = rsqrtf(q * 0.015625f + 1e-5f);
#pragma unroll
          for (int j = 0; j < 4; ++j) {
            float nv = fmaf((v[j][i] - mean) * rs, gg[j], bbv[j]);
            v[j][i] = nv;
            if (l == 0) STROW(HB, grp * 4 + i, j * 16 + ln, f2b(nv));
          }
        }
      }
    } // layer

    // ---- head: mean over t, dot w_out, sigmoid ----
    {
      float cs[4];
#pragma unroll
      for (int j = 0; j < 4; ++j) {
        float c0 = (grp < 3) ? (v[j][0] + v[j][1] + v[j][2] + v[j][3]) : 0.f;
        c0 += __shfl_xor(c0, 16);
        c0 += __shfl_xor(c0, 32);
        cs[j] = c0;
      }
      float dp = cs[0] * wo4[0] + cs[1] * wo4[1] + cs[2] * wo4[2] + cs[3] * wo4[3];
      dp += __shfl_xor(dp, 1);
      dp += __shfl_xor(dp, 2);
      dp += __shfl_xor(dp, 4);
      dp += __shfl_xor(dp, 8);
      if (lane == 0) {
        float logit = dp * (1.f / 12.f) + bo0;
        int hf = ((sp >> 4) << 4) | (sl >> 4);
        int wf = ((sp & 15) << 4) | (sl & 15);
        out[hf * 256 + wf] = 1.f / (1.f + expf(-logit));
      }
    }
  } // seq loop
#undef BT
#undef STROW
}

extern "C" void kernel_launch(void* const* d_in, const int* in_sizes, int n_in,
                              void* d_out, int out_size, void* d_ws, size_t ws_size,
                              hipStream_t stream) {
  (void)in_sizes; (void)n_in; (void)out_size; (void)ws_size;
  wpack<<<48, 256, 0, stream>>>(
      (const float*)d_in[7],  (const float*)d_in[9],
      (const float*)d_in[13], (const float*)d_in[15], (unsigned int*)d_ws);
  prithvi_fused<<<256, 1024, 0, stream>>>(
      (const float*)d_in[0],  (const float*)d_in[1],  (const float*)d_in[2],
      (const float*)d_in[3],  (const float*)d_in[4],  (const float*)d_in[5],
      (const float*)d_in[6],  (const float*)d_in[8],  (const float*)d_in[10],
      (const float*)d_in[11], (const float*)d_in[12], (const float*)d_in[14],
      (const float*)d_in[16], (const float*)d_in[17], (const float*)d_in[18],
      (const float*)d_in[19], (const float*)d_in[20], (const float*)d_ws,
      (float*)d_out);
}